// Round 16
// baseline (8902.711 us; speedup 1.0000x reference)
//
#include <hip/hip_runtime.h>
#include <hip/hip_fp16.h>
#include <math.h>

#define T_SEQ  512
#define BATCH  128
#define HID    256
#define NCLS   20
#define G4     1024   // 4*HID

typedef _Float16 v2h __attribute__((ext_vector_type(2)));

__device__ __forceinline__ float fdot2_acc(unsigned a, unsigned b, float acc) {
#if __has_builtin(__builtin_amdgcn_fdot2)
    return __builtin_amdgcn_fdot2(__builtin_bit_cast(v2h, a),
                                  __builtin_bit_cast(v2h, b), acc, false);
#else
    __half2 a2 = __builtin_bit_cast(__half2, a);
    __half2 b2 = __builtin_bit_cast(__half2, b);
    acc = fmaf(__low2float(a2),  __low2float(b2),  acc);
    acc = fmaf(__high2float(a2), __high2float(b2), acc);
    return acc;
#endif
}

// ---------------------------------------------------------------------------
// Pack U (f32 [256][1024]) -> f16x2 over k-pairs: u16[dir][kp][col].
// ---------------------------------------------------------------------------
__global__ __launch_bounds__(256) void pack_u16_v16(
    const float* __restrict__ U_f, const float* __restrict__ U_b,
    unsigned* __restrict__ u16out)
{
    int idx = blockIdx.x * 256 + threadIdx.x;    // 0 .. 2*128*1024-1
    int dir = idx >> 17;
    int rem = idx & 131071;
    int kp  = rem >> 10;
    int col = rem & 1023;
    const float* __restrict__ U = dir ? U_b : U_f;
    __half2 h = __floats2half2_rn(U[(size_t)(2 * kp) * G4 + col],
                                  U[(size_t)(2 * kp + 1) * G4 + col]);
    u16out[idx] = *(unsigned*)&h;
}

// ---------------------------------------------------------------------------
// Kernel A: batched input projection (v13, proven).
// xw[dir][s][b][col] = emb[token]@W + bias
// ---------------------------------------------------------------------------
__global__ __launch_bounds__(256) void xw_gemm_v16(
    const int*   __restrict__ tokens,
    const float* __restrict__ emb_table,
    const float* __restrict__ W_f, const float* __restrict__ b_f,
    const float* __restrict__ W_b, const float* __restrict__ b_b,
    float* __restrict__ xw, int chunk0, int chunk_len)
{
    const int dir = blockIdx.z;
    const float* __restrict__ W    = dir ? W_b : W_f;
    const float* __restrict__ bias = dir ? b_b : b_f;
    const int mtile = blockIdx.x;
    const int ntile = blockIdx.y;
    const int tid = threadIdx.x;

    __shared__ float At[256][32];
    __shared__ float Bs[32][128];
    __shared__ int   tok[32];

    if (tid < 32) {
        int m = mtile * 32 + tid;
        int s_local = m >> 7;
        int b = m & 127;
        int tt = chunk0 + s_local;
        if (dir) tt = T_SEQ - 1 - tt;
        int token = tokens[b * T_SEQ + tt];
        tok[tid] = token < 0 ? 0 : (token > 49999 ? 49999 : token);
    }
    __syncthreads();

    {
        int r = tid >> 3, c8 = tid & 7;
        const float4* src = (const float4*)(emb_table + (size_t)tok[r] * 256);
        #pragma unroll
        for (int i = 0; i < 8; ++i) {
            int c4 = c8 + i * 8;
            float4 v = src[c4];
            int k0 = c4 * 4;
            At[k0 + 0][r] = v.x; At[k0 + 1][r] = v.y;
            At[k0 + 2][r] = v.z; At[k0 + 3][r] = v.w;
        }
    }

    const int r0 = (tid >> 6) * 8;
    const int col0 = tid & 63;
    float acc0[8], acc1[8];
    {
        float bv0 = bias[ntile * 128 + col0];
        float bv1 = bias[ntile * 128 + col0 + 64];
        #pragma unroll
        for (int i = 0; i < 8; ++i) { acc0[i] = bv0; acc1[i] = bv1; }
    }

    for (int kc = 0; kc < 8; ++kc) {
        __syncthreads();
        #pragma unroll
        for (int i = 0; i < 4; ++i) {
            int idx = tid + i * 256;
            int row = idx >> 5, c4 = idx & 31;
            *(float4*)&Bs[row][c4 * 4] =
                *(const float4*)&W[(size_t)(kc * 32 + row) * G4 + ntile * 128 + c4 * 4];
        }
        __syncthreads();
        #pragma unroll 8
        for (int k = 0; k < 32; ++k) {
            float4 a0 = *(const float4*)&At[kc * 32 + k][r0];
            float4 a1 = *(const float4*)&At[kc * 32 + k][r0 + 4];
            float bb0 = Bs[k][col0];
            float bb1 = Bs[k][col0 + 64];
            acc0[0] = fmaf(a0.x, bb0, acc0[0]); acc1[0] = fmaf(a0.x, bb1, acc1[0]);
            acc0[1] = fmaf(a0.y, bb0, acc0[1]); acc1[1] = fmaf(a0.y, bb1, acc1[1]);
            acc0[2] = fmaf(a0.z, bb0, acc0[2]); acc1[2] = fmaf(a0.z, bb1, acc1[2]);
            acc0[3] = fmaf(a0.w, bb0, acc0[3]); acc1[3] = fmaf(a0.w, bb1, acc1[3]);
            acc0[4] = fmaf(a1.x, bb0, acc0[4]); acc1[4] = fmaf(a1.x, bb1, acc1[4]);
            acc0[5] = fmaf(a1.y, bb0, acc0[5]); acc1[5] = fmaf(a1.y, bb1, acc1[5]);
            acc0[6] = fmaf(a1.z, bb0, acc0[6]); acc1[6] = fmaf(a1.z, bb1, acc1[6]);
            acc0[7] = fmaf(a1.w, bb0, acc0[7]); acc1[7] = fmaf(a1.w, bb1, acc1[7]);
        }
    }

    #pragma unroll
    for (int i = 0; i < 8; ++i) {
        int m = mtile * 32 + r0 + i;
        int s_local = m >> 7, b = m & 127;
        size_t base = (((size_t)dir * chunk_len + s_local) * BATCH + b) * G4 + ntile * 128;
        xw[base + col0] = acc0[i];
        xw[base + col0 + 64] = acc1[i];
    }
}

// ---------------------------------------------------------------------------
// Kernel B: PERSISTENT scan over a whole chunk. Zero cross-block deps:
// each block owns 4 complete batch rows for one direction (recurrence is
// row-independent). grid (bg=32, dir=2) = 64 blocks x 1024 threads.
// Thread (rr = tid>>8, ci = tid&255): phase1 computes 4 gate-cols ci*4..+3
// via fdot2 over f16-packed h (LDS) x U (L2, uint4 coalesced); phase2 same
// thread = (row rr, unit ci) owns c in a register. h stays in LDS all chunk.
// ---------------------------------------------------------------------------
__global__ __launch_bounds__(1024) void lstm_scan_v16(
    const float* __restrict__ xw,          // [2][chunk][128][1024]
    const unsigned* __restrict__ u16,      // [2][128][1024]
    float* __restrict__ h_state,           // [2][128][256]
    float* __restrict__ c_state,           // [2][128][256]
    int chunk_len)
{
    const int bg  = blockIdx.x;            // rows bg*4 .. bg*4+3
    const int dir = blockIdx.y;
    const int tid = threadIdx.x;
    const unsigned* __restrict__ U16 = u16 + (size_t)dir * 131072;

    __shared__ float    zs[4][1024];       // z tile, 16 KB
    __shared__ float    hsf[4][256];       // h f32, 4 KB
    __shared__ unsigned hs16[4][128];      // h f16x2 packed, 2 KB

    const int rr = tid >> 8;               // 0..3
    const int ci = tid & 255;              // unit / col-group
    const int c0 = ci * 4;
    const size_t gidx = ((size_t)dir * BATCH + bg * 4 + rr) * HID + ci;

    hsf[rr][ci] = h_state[gidx];
    float creg  = c_state[gidx];
    __syncthreads();
    if (tid < 512) {
        int r3 = tid >> 7, kp = tid & 127;
        __half2 hh = __floats2half2_rn(hsf[r3][2 * kp], hsf[r3][2 * kp + 1]);
        hs16[r3][kp] = *(unsigned*)&hh;
    }
    __syncthreads();

    for (int sl = 0; sl < chunk_len; ++sl) {
        // ---- phase 1: z = xw + h@U (4 cols/thread) ----
        float4 xv = *(const float4*)&xw[(((size_t)dir * chunk_len + sl) * BATCH
                                         + bg * 4 + rr) * G4 + c0];
        float a0 = xv.x, a1 = xv.y, a2 = xv.z, a3 = xv.w;
        const unsigned* __restrict__ Up = U16 + c0;
        #pragma unroll 8
        for (int kp = 0; kp < 128; ++kp) {
            unsigned hp = hs16[rr][kp];                    // wave broadcast
            uint4 uv = *(const uint4*)&Up[(size_t)kp * G4]; // 1 KB/wave coalesced
            a0 = fdot2_acc(hp, uv.x, a0);
            a1 = fdot2_acc(hp, uv.y, a1);
            a2 = fdot2_acc(hp, uv.z, a2);
            a3 = fdot2_acc(hp, uv.w, a3);
        }
        zs[rr][c0 + 0] = a0; zs[rr][c0 + 1] = a1;
        zs[rr][c0 + 2] = a2; zs[rr][c0 + 3] = a3;
        __syncthreads();

        // ---- phase 2: gates -> c,h for (row rr, unit ci) ----
        {
            float zi = zs[rr][ci];
            float zf = zs[rr][256 + ci];
            float zg = zs[rr][512 + ci];
            float zo = zs[rr][768 + ci];
            float si = 1.0f / (1.0f + expf(-zi));
            float sf = 1.0f / (1.0f + expf(-zf));
            float tg = tanhf(zg);
            float so = 1.0f / (1.0f + expf(-zo));
            creg = fmaf(sf, creg, si * tg);
            hsf[rr][ci] = so * tanhf(creg);
        }
        __syncthreads();

        // ---- repack h -> f16x2 ----
        if (tid < 512) {
            int r3 = tid >> 7, kp = tid & 127;
            __half2 hh = __floats2half2_rn(hsf[r3][2 * kp], hsf[r3][2 * kp + 1]);
            hs16[r3][kp] = *(unsigned*)&hh;
        }
        __syncthreads();
    }

    h_state[gidx] = hsf[rr][ci];
    c_state[gidx] = creg;
}

// ---------------------------------------------------------------------------
// Fallback per-step kernel (v12 path) for tiny workspace.
// ---------------------------------------------------------------------------
__global__ __launch_bounds__(256) void lstm_step_fb(
    const int*   __restrict__ tokens,
    const float* __restrict__ emb_table,
    const float* __restrict__ W_f, const float* __restrict__ U_f, const float* __restrict__ b_f,
    const float* __restrict__ W_b, const float* __restrict__ U_b, const float* __restrict__ b_b,
    const float* __restrict__ h_in, float* __restrict__ h_out,
    float* __restrict__ c_state, int step)
{
    const int rt  = blockIdx.x;
    const int ut  = blockIdx.y;
    const int dir = blockIdx.z;
    const int tid = threadIdx.x;
    const float* __restrict__ W  = dir ? W_b : W_f;
    const float* __restrict__ U  = dir ? U_b : U_f;
    const float* __restrict__ bs = dir ? b_b : b_f;

    __shared__ int   tok[8];
    __shared__ float xs[8][260];
    __shared__ float hs[8][260];
    __shared__ float zsf[4][8][32];

    const int tt = dir ? (T_SEQ - 1 - step) : step;
    if (tid < 8) {
        int token = tokens[(rt * 8 + tid) * T_SEQ + tt];
        tok[tid] = (token < 0) ? 0 : (token > 49999 ? 49999 : token);
    }
    __syncthreads();
    for (int i = tid; i < 2048; i += 256) {
        int r = i >> 8, k = i & 255;
        xs[r][k] = emb_table[(size_t)tok[r] * 256 + k];
        hs[r][k] = h_in[((size_t)dir * BATCH + rt * 8 + r) * HID + k];
    }
    __syncthreads();

    const int g = tid >> 6, r = (tid >> 3) & 7, q = tid & 7;
    const int col = g * 256 + ut * 32 + q * 4;
    const float4* __restrict__ W4 = (const float4*)(W + col);
    const float4* __restrict__ U4 = (const float4*)(U + col);
    float4 acc = *(const float4*)(bs + col);
    #pragma unroll 4
    for (int k = 0; k < 256; ++k) {
        float xv = xs[r][k], hv = hs[r][k];
        float4 w = W4[(size_t)k * 256];
        float4 u = U4[(size_t)k * 256];
        acc.x = fmaf(xv, w.x, acc.x); acc.y = fmaf(xv, w.y, acc.y);
        acc.z = fmaf(xv, w.z, acc.z); acc.w = fmaf(xv, w.w, acc.w);
        acc.x = fmaf(hv, u.x, acc.x); acc.y = fmaf(hv, u.y, acc.y);
        acc.z = fmaf(hv, u.z, acc.z); acc.w = fmaf(hv, u.w, acc.w);
    }
    *(float4*)&zsf[g][r][q * 4] = acc;
    __syncthreads();
    {
        const int r2 = tid >> 5, j2 = tid & 31;
        float si = 1.0f / (1.0f + expf(-zsf[0][r2][j2]));
        float sf = 1.0f / (1.0f + expf(-zsf[1][r2][j2]));
        float tg = tanhf(zsf[2][r2][j2]);
        float so = 1.0f / (1.0f + expf(-zsf[3][r2][j2]));
        size_t idx = ((size_t)dir * BATCH + rt * 8 + r2) * HID + ut * 32 + j2;
        float cv = fmaf(sf, c_state[idx], si * tg);
        c_state[idx] = cv;
        h_out[idx] = so * tanhf(cv);
    }
}

// ---------------------------------------------------------------------------
// Dense + softmax (f32): one block per batch row.
// ---------------------------------------------------------------------------
__global__ __launch_bounds__(64) void dense_softmax_v16(
    const float* __restrict__ h_final,
    const float* __restrict__ W_d, const float* __restrict__ b_d,
    float* __restrict__ out)
{
    const int rrow = blockIdx.x;
    const int cth  = threadIdx.x;
    __shared__ float lg[NCLS];
    if (cth < NCLS) {
        const float* hf = h_final + (size_t)rrow * HID;
        const float* hb = h_final + ((size_t)BATCH + rrow) * HID;
        float s = b_d[cth];
        for (int k = 0; k < HID; ++k) s = fmaf(hf[k], W_d[k * NCLS + cth], s);
        for (int k = 0; k < HID; ++k) s = fmaf(hb[k], W_d[(HID + k) * NCLS + cth], s);
        lg[cth] = s;
    }
    __syncthreads();
    if (cth == 0) {
        float m = lg[0];
        for (int c = 1; c < NCLS; ++c) m = fmaxf(m, lg[c]);
        float e[NCLS]; float ssum = 0.0f;
        for (int c = 0; c < NCLS; ++c) { e[c] = expf(lg[c] - m); ssum += e[c]; }
        float inv = 1.0f / ssum;
        for (int c = 0; c < NCLS; ++c) out[rrow * NCLS + c] = e[c] * inv;
    }
}

extern "C" void kernel_launch(void* const* d_in, const int* in_sizes, int n_in,
                              void* d_out, int out_size, void* d_ws, size_t ws_size,
                              hipStream_t stream)
{
    const int*   tokens = (const int*)d_in[0];
    const float* emb    = (const float*)d_in[1];
    const float* W_f    = (const float*)d_in[2];
    const float* U_f    = (const float*)d_in[3];
    const float* b_f    = (const float*)d_in[4];
    const float* W_b    = (const float*)d_in[5];
    const float* U_b    = (const float*)d_in[6];
    const float* b_b    = (const float*)d_in[7];
    const float* W_d    = (const float*)d_in[8];
    const float* b_d    = (const float*)d_in[9];
    float* out = (float*)d_out;
    float* ws  = (float*)d_ws;

    const size_t HSLOT = (size_t)2 * BATCH * HID;        // 65536 floats
    const size_t U16SZ = (size_t)2 * 128 * G4;           // 262144 dwords
    int chunk = 0;
    const int cand[4] = {512, 128, 64, 16};
    for (int i = 0; i < 4; ++i) {
        size_t need = ((size_t)2 * cand[i] * BATCH * G4 + 2 * HSLOT + U16SZ) * sizeof(float);
        if (ws_size >= need) { chunk = cand[i]; break; }
    }

    if (chunk == 0) {
        float* hbuf0 = ws;
        float* cbuf  = hbuf0 + HSLOT;
        float* hbuf1 = cbuf + HSLOT;
        hipMemsetAsync(hbuf0, 0, 2 * HSLOT * sizeof(float), stream);
        float* hin = hbuf0; float* hout = hbuf1;
        for (int s = 0; s < T_SEQ; ++s) {
            lstm_step_fb<<<dim3(16, 8, 2), 256, 0, stream>>>(
                tokens, emb, W_f, U_f, b_f, W_b, U_b, b_b, hin, hout, cbuf, s);
            float* tmp = hin; hin = hout; hout = tmp;
        }
        dense_softmax_v16<<<dim3(BATCH), 64, 0, stream>>>(hin, W_d, b_d, out);
        return;
    }

    float*    xw     = ws;                                  // [2][chunk][128][1024]
    float*    hstate = xw + (size_t)2 * chunk * BATCH * G4; // [2][128][256]
    float*    cstate = hstate + HSLOT;                      // [2][128][256]
    unsigned* u16    = (unsigned*)(cstate + HSLOT);         // [2][128][1024]

    hipMemsetAsync(hstate, 0, 2 * HSLOT * sizeof(float), stream);  // h0 + c0

    pack_u16_v16<<<dim3(1024), 256, 0, stream>>>(U_f, U_b, u16);

    for (int c0 = 0; c0 < T_SEQ; c0 += chunk) {
        xw_gemm_v16<<<dim3(chunk * BATCH / 32, 8, 2), 256, 0, stream>>>(
            tokens, emb, W_f, b_f, W_b, b_b, xw, c0, chunk);
        lstm_scan_v16<<<dim3(32, 2), 1024, 0, stream>>>(
            xw, u16, hstate, cstate, chunk);
    }
    dense_softmax_v16<<<dim3(BATCH), 64, 0, stream>>>(hstate, W_d, b_d, out);
}

// Round 17
// 3032.296 us; speedup vs baseline: 2.9360x; 2.9360x over previous
//
#include <hip/hip_runtime.h>
#include <hip/hip_fp16.h>
#include <math.h>

#define T_SEQ  512
#define BATCH  128
#define HID    256
#define NCLS   20
#define G4     1024   // 4*HID

typedef _Float16 v2h __attribute__((ext_vector_type(2)));

__device__ __forceinline__ float fdot2_acc(unsigned a, unsigned b, float acc) {
#if __has_builtin(__builtin_amdgcn_fdot2)
    return __builtin_amdgcn_fdot2(__builtin_bit_cast(v2h, a),
                                  __builtin_bit_cast(v2h, b), acc, false);
#else
    __half2 a2 = __builtin_bit_cast(__half2, a);
    __half2 b2 = __builtin_bit_cast(__half2, b);
    acc = fmaf(__low2float(a2),  __low2float(b2),  acc);
    acc = fmaf(__high2float(a2), __high2float(b2), acc);
    return acc;
#endif
}

// ---------------------------------------------------------------------------
// Pack U (f32 [256][1024]) -> f16x2 over k-pairs: u16[dir][kp][col].
// ---------------------------------------------------------------------------
__global__ __launch_bounds__(256) void pack_u16_v17(
    const float* __restrict__ U_f, const float* __restrict__ U_b,
    unsigned* __restrict__ u16out)
{
    int idx = blockIdx.x * 256 + threadIdx.x;    // 0 .. 2*128*1024-1
    int dir = idx >> 17;
    int rem = idx & 131071;
    int kp  = rem >> 10;
    int col = rem & 1023;
    const float* __restrict__ U = dir ? U_b : U_f;
    __half2 h = __floats2half2_rn(U[(size_t)(2 * kp) * G4 + col],
                                  U[(size_t)(2 * kp + 1) * G4 + col]);
    u16out[idx] = *(unsigned*)&h;
}

// ---------------------------------------------------------------------------
// Kernel A: batched input projection (proven v13 structure).
// xw[dir][s][b][col] = emb[token]@W + bias
// ---------------------------------------------------------------------------
__global__ __launch_bounds__(256) void xw_gemm_v17(
    const int*   __restrict__ tokens,
    const float* __restrict__ emb_table,
    const float* __restrict__ W_f, const float* __restrict__ b_f,
    const float* __restrict__ W_b, const float* __restrict__ b_b,
    float* __restrict__ xw, int chunk0, int chunk_len)
{
    const int dir = blockIdx.z;
    const float* __restrict__ W    = dir ? W_b : W_f;
    const float* __restrict__ bias = dir ? b_b : b_f;
    const int mtile = blockIdx.x;
    const int ntile = blockIdx.y;
    const int tid = threadIdx.x;

    __shared__ float At[256][32];
    __shared__ float Bs[32][128];
    __shared__ int   tok[32];

    if (tid < 32) {
        int m = mtile * 32 + tid;
        int s_local = m >> 7;
        int b = m & 127;
        int tt = chunk0 + s_local;
        if (dir) tt = T_SEQ - 1 - tt;
        int token = tokens[b * T_SEQ + tt];
        tok[tid] = token < 0 ? 0 : (token > 49999 ? 49999 : token);
    }
    __syncthreads();

    {
        int r = tid >> 3, c8 = tid & 7;
        const float4* src = (const float4*)(emb_table + (size_t)tok[r] * 256);
        #pragma unroll
        for (int i = 0; i < 8; ++i) {
            int c4 = c8 + i * 8;
            float4 v = src[c4];
            int k0 = c4 * 4;
            At[k0 + 0][r] = v.x; At[k0 + 1][r] = v.y;
            At[k0 + 2][r] = v.z; At[k0 + 3][r] = v.w;
        }
    }

    const int r0 = (tid >> 6) * 8;
    const int col0 = tid & 63;
    float acc0[8], acc1[8];
    {
        float bv0 = bias[ntile * 128 + col0];
        float bv1 = bias[ntile * 128 + col0 + 64];
        #pragma unroll
        for (int i = 0; i < 8; ++i) { acc0[i] = bv0; acc1[i] = bv1; }
    }

    for (int kc = 0; kc < 8; ++kc) {
        __syncthreads();
        #pragma unroll
        for (int i = 0; i < 4; ++i) {
            int idx = tid + i * 256;
            int row = idx >> 5, c4 = idx & 31;
            *(float4*)&Bs[row][c4 * 4] =
                *(const float4*)&W[(size_t)(kc * 32 + row) * G4 + ntile * 128 + c4 * 4];
        }
        __syncthreads();
        #pragma unroll 8
        for (int k = 0; k < 32; ++k) {
            float4 a0 = *(const float4*)&At[kc * 32 + k][r0];
            float4 a1 = *(const float4*)&At[kc * 32 + k][r0 + 4];
            float bb0 = Bs[k][col0];
            float bb1 = Bs[k][col0 + 64];
            acc0[0] = fmaf(a0.x, bb0, acc0[0]); acc1[0] = fmaf(a0.x, bb1, acc1[0]);
            acc0[1] = fmaf(a0.y, bb0, acc0[1]); acc1[1] = fmaf(a0.y, bb1, acc1[1]);
            acc0[2] = fmaf(a0.z, bb0, acc0[2]); acc1[2] = fmaf(a0.z, bb1, acc1[2]);
            acc0[3] = fmaf(a0.w, bb0, acc0[3]); acc1[3] = fmaf(a0.w, bb1, acc1[3]);
            acc0[4] = fmaf(a1.x, bb0, acc0[4]); acc1[4] = fmaf(a1.x, bb1, acc1[4]);
            acc0[5] = fmaf(a1.y, bb0, acc0[5]); acc1[5] = fmaf(a1.y, bb1, acc1[5]);
            acc0[6] = fmaf(a1.z, bb0, acc0[6]); acc1[6] = fmaf(a1.z, bb1, acc1[6]);
            acc0[7] = fmaf(a1.w, bb0, acc0[7]); acc1[7] = fmaf(a1.w, bb1, acc1[7]);
        }
    }

    #pragma unroll
    for (int i = 0; i < 8; ++i) {
        int m = mtile * 32 + r0 + i;
        int s_local = m >> 7, b = m & 127;
        size_t base = (((size_t)dir * chunk_len + s_local) * BATCH + b) * G4 + ntile * 128;
        xw[base + col0] = acc0[i];
        xw[base + col0 + 64] = acc1[i];
    }
}

// ---------------------------------------------------------------------------
// Kernel B: persistent scan, U read ONCE per block per step.
// grid (bg=64, dir=2) = 128 blocks x 1024 threads. Block owns rows bg*2,+1.
// Phase 1: thread ci in [0,1024) = one gate-col, BOTH rows share its single
// U dword (register reuse): per kp {1 coalesced U load + 2 LDS h-broadcast
// + 2 fdot2}, 16-deep double-buffered prefetch. Per-block U = 0.5 MB/step.
// Phase 2: threads 0..255 = (row, unit-pair); c + last-h in registers;
// packs new h directly into hs16. Two __syncthreads per step.
// ---------------------------------------------------------------------------
__global__ __launch_bounds__(1024) void lstm_scan_v17(
    const float* __restrict__ xw,          // [2][chunk][128][1024]
    const unsigned* __restrict__ u16,      // [2][128][1024]
    float* __restrict__ h_state,           // [2][128][256]
    float* __restrict__ c_state,           // [2][128][256]
    int chunk_len)
{
    const int bg  = blockIdx.x;            // rows bg*2, bg*2+1
    const int dir = blockIdx.y;
    const int tid = threadIdx.x;
    const unsigned* __restrict__ U16 = u16 + (size_t)dir * 131072;

    __shared__ unsigned hs16[2][128];      // h packed f16x2 over k, 1 KB
    __shared__ float    zs[2][1024];       // z for both rows, 8 KB

    const int row0 = bg * 2;

    // phase-2 persona state (threads 0..255): rr = tid>>7, unit pair up=tid&127
    const int rr = tid >> 7;
    const int up = tid & 127;
    float c0r = 0.0f, c1r = 0.0f, h0r = 0.0f, h1r = 0.0f;
    if (tid < 256) {
        size_t base = ((size_t)dir * BATCH + row0 + rr) * HID + 2 * up;
        c0r = c_state[base];
        c1r = c_state[base + 1];
        float a = h_state[base];
        float b = h_state[base + 1];
        h0r = a; h1r = b;
        __half2 hh = __floats2half2_rn(a, b);
        hs16[rr][up] = *(unsigned*)&hh;
    }
    __syncthreads();

    for (int sl = 0; sl < chunk_len; ++sl) {
        // ---- phase 1: z[row][ci] = xw + h@U ----
        const float* xwp = xw + (((size_t)dir * chunk_len + sl) * BATCH + row0) * G4;
        float acc0 = xwp[tid];
        float acc1 = xwp[G4 + tid];

        unsigned ub[16], un[16];
        #pragma unroll
        for (int j = 0; j < 16; ++j) ub[j] = U16[(size_t)j * G4 + tid];
        #pragma unroll
        for (int blk = 0; blk < 8; ++blk) {
            int nb = (blk + 1) & 7;        // wrap: last prefetch re-reads blk0 (cheap, L1-hot)
            #pragma unroll
            for (int j = 0; j < 16; ++j)
                un[j] = U16[(size_t)(nb * 16 + j) * G4 + tid];
            #pragma unroll
            for (int j = 0; j < 16; ++j) {
                int kp = blk * 16 + j;
                unsigned h0 = hs16[0][kp];
                unsigned h1 = hs16[1][kp];
                acc0 = fdot2_acc(h0, ub[j], acc0);
                acc1 = fdot2_acc(h1, ub[j], acc1);
            }
            #pragma unroll
            for (int j = 0; j < 16; ++j) ub[j] = un[j];
        }
        zs[0][tid] = acc0;
        zs[1][tid] = acc1;
        __syncthreads();

        // ---- phase 2: gates -> c,h for (rr, units 2up, 2up+1) ----
        if (tid < 256) {
            float zi0 = zs[rr][2 * up],       zi1 = zs[rr][2 * up + 1];
            float zf0 = zs[rr][256 + 2 * up], zf1 = zs[rr][256 + 2 * up + 1];
            float zg0 = zs[rr][512 + 2 * up], zg1 = zs[rr][512 + 2 * up + 1];
            float zo0 = zs[rr][768 + 2 * up], zo1 = zs[rr][768 + 2 * up + 1];
            float si0 = 1.0f / (1.0f + expf(-zi0)), si1 = 1.0f / (1.0f + expf(-zi1));
            float sf0 = 1.0f / (1.0f + expf(-zf0)), sf1 = 1.0f / (1.0f + expf(-zf1));
            float tg0 = tanhf(zg0),                 tg1 = tanhf(zg1);
            float so0 = 1.0f / (1.0f + expf(-zo0)), so1 = 1.0f / (1.0f + expf(-zo1));
            c0r = fmaf(sf0, c0r, si0 * tg0);
            c1r = fmaf(sf1, c1r, si1 * tg1);
            h0r = so0 * tanhf(c0r);
            h1r = so1 * tanhf(c1r);
            __half2 hh = __floats2half2_rn(h0r, h1r);
            hs16[rr][up] = *(unsigned*)&hh;
        }
        __syncthreads();
    }

    if (tid < 256) {
        size_t base = ((size_t)dir * BATCH + row0 + rr) * HID + 2 * up;
        h_state[base]     = h0r;
        h_state[base + 1] = h1r;
        c_state[base]     = c0r;
        c_state[base + 1] = c1r;
    }
}

// ---------------------------------------------------------------------------
// Fallback per-step kernel (v12 path) for tiny workspace.
// ---------------------------------------------------------------------------
__global__ __launch_bounds__(256) void lstm_step_fb(
    const int*   __restrict__ tokens,
    const float* __restrict__ emb_table,
    const float* __restrict__ W_f, const float* __restrict__ U_f, const float* __restrict__ b_f,
    const float* __restrict__ W_b, const float* __restrict__ U_b, const float* __restrict__ b_b,
    const float* __restrict__ h_in, float* __restrict__ h_out,
    float* __restrict__ c_state, int step)
{
    const int rt  = blockIdx.x;
    const int ut  = blockIdx.y;
    const int dir = blockIdx.z;
    const int tid = threadIdx.x;
    const float* __restrict__ W  = dir ? W_b : W_f;
    const float* __restrict__ U  = dir ? U_b : U_f;
    const float* __restrict__ bs = dir ? b_b : b_f;

    __shared__ int   tok[8];
    __shared__ float xs[8][260];
    __shared__ float hs[8][260];
    __shared__ float zsf[4][8][32];

    const int tt = dir ? (T_SEQ - 1 - step) : step;
    if (tid < 8) {
        int token = tokens[(rt * 8 + tid) * T_SEQ + tt];
        tok[tid] = (token < 0) ? 0 : (token > 49999 ? 49999 : token);
    }
    __syncthreads();
    for (int i = tid; i < 2048; i += 256) {
        int r = i >> 8, k = i & 255;
        xs[r][k] = emb_table[(size_t)tok[r] * 256 + k];
        hs[r][k] = h_in[((size_t)dir * BATCH + rt * 8 + r) * HID + k];
    }
    __syncthreads();

    const int g = tid >> 6, r = (tid >> 3) & 7, q = tid & 7;
    const int col = g * 256 + ut * 32 + q * 4;
    const float4* __restrict__ W4 = (const float4*)(W + col);
    const float4* __restrict__ U4 = (const float4*)(U + col);
    float4 acc = *(const float4*)(bs + col);
    #pragma unroll 4
    for (int k = 0; k < 256; ++k) {
        float xv = xs[r][k], hv = hs[r][k];
        float4 w = W4[(size_t)k * 256];
        float4 u = U4[(size_t)k * 256];
        acc.x = fmaf(xv, w.x, acc.x); acc.y = fmaf(xv, w.y, acc.y);
        acc.z = fmaf(xv, w.z, acc.z); acc.w = fmaf(xv, w.w, acc.w);
        acc.x = fmaf(hv, u.x, acc.x); acc.y = fmaf(hv, u.y, acc.y);
        acc.z = fmaf(hv, u.z, acc.z); acc.w = fmaf(hv, u.w, acc.w);
    }
    *(float4*)&zsf[g][r][q * 4] = acc;
    __syncthreads();
    {
        const int r2 = tid >> 5, j2 = tid & 31;
        float si = 1.0f / (1.0f + expf(-zsf[0][r2][j2]));
        float sf = 1.0f / (1.0f + expf(-zsf[1][r2][j2]));
        float tg = tanhf(zsf[2][r2][j2]);
        float so = 1.0f / (1.0f + expf(-zsf[3][r2][j2]));
        size_t idx = ((size_t)dir * BATCH + rt * 8 + r2) * HID + ut * 32 + j2;
        float cv = fmaf(sf, c_state[idx], si * tg);
        c_state[idx] = cv;
        h_out[idx] = so * tanhf(cv);
    }
}

// ---------------------------------------------------------------------------
// Dense + softmax (f32): one block per batch row.
// ---------------------------------------------------------------------------
__global__ __launch_bounds__(64) void dense_softmax_v17(
    const float* __restrict__ h_final,
    const float* __restrict__ W_d, const float* __restrict__ b_d,
    float* __restrict__ out)
{
    const int rrow = blockIdx.x;
    const int cth  = threadIdx.x;
    __shared__ float lg[NCLS];
    if (cth < NCLS) {
        const float* hf = h_final + (size_t)rrow * HID;
        const float* hb = h_final + ((size_t)BATCH + rrow) * HID;
        float s = b_d[cth];
        for (int k = 0; k < HID; ++k) s = fmaf(hf[k], W_d[k * NCLS + cth], s);
        for (int k = 0; k < HID; ++k) s = fmaf(hb[k], W_d[(HID + k) * NCLS + cth], s);
        lg[cth] = s;
    }
    __syncthreads();
    if (cth == 0) {
        float m = lg[0];
        for (int c = 1; c < NCLS; ++c) m = fmaxf(m, lg[c]);
        float e[NCLS]; float ssum = 0.0f;
        for (int c = 0; c < NCLS; ++c) { e[c] = expf(lg[c] - m); ssum += e[c]; }
        float inv = 1.0f / ssum;
        for (int c = 0; c < NCLS; ++c) out[rrow * NCLS + c] = e[c] * inv;
    }
}

extern "C" void kernel_launch(void* const* d_in, const int* in_sizes, int n_in,
                              void* d_out, int out_size, void* d_ws, size_t ws_size,
                              hipStream_t stream)
{
    const int*   tokens = (const int*)d_in[0];
    const float* emb    = (const float*)d_in[1];
    const float* W_f    = (const float*)d_in[2];
    const float* U_f    = (const float*)d_in[3];
    const float* b_f    = (const float*)d_in[4];
    const float* W_b    = (const float*)d_in[5];
    const float* U_b    = (const float*)d_in[6];
    const float* b_b    = (const float*)d_in[7];
    const float* W_d    = (const float*)d_in[8];
    const float* b_d    = (const float*)d_in[9];
    float* out = (float*)d_out;
    float* ws  = (float*)d_ws;

    const size_t HSLOT = (size_t)2 * BATCH * HID;        // 65536 floats
    const size_t U16SZ = (size_t)2 * 128 * G4;           // 262144 dwords
    int chunk = 0;
    const int cand[4] = {512, 128, 64, 16};
    for (int i = 0; i < 4; ++i) {
        size_t need = ((size_t)2 * cand[i] * BATCH * G4 + 2 * HSLOT + U16SZ) * sizeof(float);
        if (ws_size >= need) { chunk = cand[i]; break; }
    }

    if (chunk == 0) {
        float* hbuf0 = ws;
        float* cbuf  = hbuf0 + HSLOT;
        float* hbuf1 = cbuf + HSLOT;
        hipMemsetAsync(hbuf0, 0, 2 * HSLOT * sizeof(float), stream);
        float* hin = hbuf0; float* hout = hbuf1;
        for (int s = 0; s < T_SEQ; ++s) {
            lstm_step_fb<<<dim3(16, 8, 2), 256, 0, stream>>>(
                tokens, emb, W_f, U_f, b_f, W_b, U_b, b_b, hin, hout, cbuf, s);
            float* tmp = hin; hin = hout; hout = tmp;
        }
        dense_softmax_v17<<<dim3(BATCH), 64, 0, stream>>>(hin, W_d, b_d, out);
        return;
    }

    float*    xw     = ws;                                  // [2][chunk][128][1024]
    float*    hstate = xw + (size_t)2 * chunk * BATCH * G4; // [2][128][256]
    float*    cstate = hstate + HSLOT;                      // [2][128][256]
    unsigned* u16    = (unsigned*)(cstate + HSLOT);         // [2][128][1024]

    hipMemsetAsync(hstate, 0, 2 * HSLOT * sizeof(float), stream);  // h0 + c0

    pack_u16_v17<<<dim3(1024), 256, 0, stream>>>(U_f, U_b, u16);

    for (int c0 = 0; c0 < T_SEQ; c0 += chunk) {
        xw_gemm_v17<<<dim3(chunk * BATCH / 32, 8, 2), 256, 0, stream>>>(
            tokens, emb, W_f, b_f, W_b, b_b, xw, c0, chunk);
        lstm_scan_v17<<<dim3(64, 2), 1024, 0, stream>>>(
            xw, u16, hstate, cstate, chunk);
    }
    dense_softmax_v17<<<dim3(BATCH), 64, 0, stream>>>(hstate, W_d, b_d, out);
}

// Round 18
// 2297.367 us; speedup vs baseline: 3.8752x; 1.3199x over previous
//
#include <hip/hip_runtime.h>
#include <hip/hip_fp16.h>
#include <math.h>

#define T_SEQ  512
#define BATCH  128
#define HID    256
#define NCLS   20
#define G4     1024   // 4*HID

typedef _Float16 v2h  __attribute__((ext_vector_type(2)));
typedef _Float16 f16x8 __attribute__((ext_vector_type(8)));
typedef float    f32x4 __attribute__((ext_vector_type(4)));

__device__ __forceinline__ float fdot2_acc(unsigned a, unsigned b, float acc) {
#if __has_builtin(__builtin_amdgcn_fdot2)
    return __builtin_amdgcn_fdot2(__builtin_bit_cast(v2h, a),
                                  __builtin_bit_cast(v2h, b), acc, false);
#else
    __half2 a2 = __builtin_bit_cast(__half2, a);
    __half2 b2 = __builtin_bit_cast(__half2, b);
    acc = fmaf(__low2float(a2),  __low2float(b2),  acc);
    acc = fmaf(__high2float(a2), __high2float(b2), acc);
    return acc;
#endif
}

// ---------------------------------------------------------------------------
// Pack U (f32 [256][1024]) -> f16x2 over k-pairs: u16[dir][kp][col].
// ---------------------------------------------------------------------------
__global__ __launch_bounds__(256) void pack_u16_v18(
    const float* __restrict__ U_f, const float* __restrict__ U_b,
    unsigned* __restrict__ u16out)
{
    int idx = blockIdx.x * 256 + threadIdx.x;    // 0 .. 2*128*1024-1
    int dir = idx >> 17;
    int rem = idx & 131071;
    int kp  = rem >> 10;
    int col = rem & 1023;
    const float* __restrict__ U = dir ? U_b : U_f;
    __half2 h = __floats2half2_rn(U[(size_t)(2 * kp) * G4 + col],
                                  U[(size_t)(2 * kp + 1) * G4 + col]);
    u16out[idx] = *(unsigned*)&h;
}

// ---------------------------------------------------------------------------
// Kernel A (NEW): input projection via f16 MFMA (16x16x32).
// xw[dir][s][b][col] = emb[token] @ W + bias, f32 out.
// grid (mtiles = chunk*128/32, ntiles = 4, dir = 2), block 256 (4 waves).
// Block tile: M=32 rows x N=256 cols, K=256.
// A (emb, f16) resident in LDS [32][264]; W staged per-BK=32 transposed
// Wt[256][40] f16. Wave w owns cols w*64..+63: frags 2(M) x 4(N).
// Layouts (AMD lab notes / m89): A[l&15][8*(l>>4)+j]; B[8*(l>>4)+j][l&15];
// D: col=l&15, row=(l>>4)*4+reg.
// ---------------------------------------------------------------------------
__global__ __launch_bounds__(256) void xw_gemm_mfma_v18(
    const int*   __restrict__ tokens,
    const float* __restrict__ emb_table,
    const float* __restrict__ W_f, const float* __restrict__ b_f,
    const float* __restrict__ W_b, const float* __restrict__ b_b,
    float* __restrict__ xw, int chunk0, int chunk_len)
{
    const int dir = blockIdx.z;
    const float* __restrict__ W    = dir ? W_b : W_f;
    const float* __restrict__ bias = dir ? b_b : b_f;
    const int mtile = blockIdx.x;
    const int ntile = blockIdx.y;          // 0..3 (256 cols each)
    const int tid = threadIdx.x;

    __shared__ _Float16 Ah[32][264];       // A f16, padded (16.9 KB)
    __shared__ _Float16 Wt[256][40];       // W^T chunk f16, padded (20 KB)
    __shared__ int tok[32];

    if (tid < 32) {
        int m = mtile * 32 + tid;
        int s_local = m >> 7;
        int b = m & 127;
        int tt = chunk0 + s_local;
        if (dir) tt = T_SEQ - 1 - tt;
        int token = tokens[b * T_SEQ + tt];
        tok[tid] = token < 0 ? 0 : (token > 49999 ? 49999 : token);
    }
    __syncthreads();

    {   // gather 32 emb rows -> f16 LDS
        int r = tid >> 3, c8 = tid & 7;
        const float4* src = (const float4*)(emb_table + (size_t)tok[r] * 256);
        #pragma unroll
        for (int i = 0; i < 8; ++i) {
            int c4 = c8 + i * 8;
            float4 v = src[c4];
            int k0 = c4 * 4;
            Ah[r][k0 + 0] = (_Float16)v.x;
            Ah[r][k0 + 1] = (_Float16)v.y;
            Ah[r][k0 + 2] = (_Float16)v.z;
            Ah[r][k0 + 3] = (_Float16)v.w;
        }
    }

    const int wv   = tid >> 6;             // wave 0..3 -> cols wv*64..+63
    const int lane = tid & 63;
    const int lr   = lane & 15;
    const int koff = (lane >> 4) * 8;
    const int n0   = wv * 64;

    f32x4 acc0[4], acc1[4];
    #pragma unroll
    for (int nf = 0; nf < 4; ++nf) {
        float bv = bias[ntile * 256 + n0 + nf * 16 + lr];
        acc0[nf] = (f32x4){bv, bv, bv, bv};
        acc1[nf] = (f32x4){bv, bv, bv, bv};
    }

    for (int kc = 0; kc < 8; ++kc) {
        __syncthreads();
        // stage W chunk transposed: Wt[n][k] = W[kc*32+k][ntile*256+n]
        #pragma unroll
        for (int i = 0; i < 32; ++i) {
            int idx = tid + i * 256;       // 0..8191
            int k = idx >> 8, n = idx & 255;
            Wt[n][k] = (_Float16)W[(size_t)(kc * 32 + k) * G4 + ntile * 256 + n];
        }
        __syncthreads();

        f16x8 a0 = *(const f16x8*)&Ah[lr][kc * 32 + koff];
        f16x8 a1 = *(const f16x8*)&Ah[16 + lr][kc * 32 + koff];
        #pragma unroll
        for (int nf = 0; nf < 4; ++nf) {
            f16x8 bf = *(const f16x8*)&Wt[n0 + nf * 16 + lr][koff];
            acc0[nf] = __builtin_amdgcn_mfma_f32_16x16x32_f16(a0, bf, acc0[nf], 0, 0, 0);
            acc1[nf] = __builtin_amdgcn_mfma_f32_16x16x32_f16(a1, bf, acc1[nf], 0, 0, 0);
        }
    }

    // store: D row=(lane>>4)*4+i (within 16), col=lr
    const int rbase = (lane >> 4) * 4;
    #pragma unroll
    for (int m = 0; m < 2; ++m) {
        #pragma unroll
        for (int nf = 0; nf < 4; ++nf) {
            f32x4 av = m ? acc1[nf] : acc0[nf];
            #pragma unroll
            for (int i = 0; i < 4; ++i) {
                int mrow = mtile * 32 + m * 16 + rbase + i;
                int s_local = mrow >> 7, b = mrow & 127;
                int col = ntile * 256 + n0 + nf * 16 + lr;
                xw[(((size_t)dir * chunk_len + s_local) * BATCH + b) * G4 + col] = av[i];
            }
        }
    }
}

// ---------------------------------------------------------------------------
// Kernel B: persistent scan (v17, proven: 4.15 us/step = per-CU L2 floor).
// ---------------------------------------------------------------------------
__global__ __launch_bounds__(1024) void lstm_scan_v18(
    const float* __restrict__ xw,          // [2][chunk][128][1024]
    const unsigned* __restrict__ u16,      // [2][128][1024]
    float* __restrict__ h_state,           // [2][128][256]
    float* __restrict__ c_state,           // [2][128][256]
    int chunk_len)
{
    const int bg  = blockIdx.x;            // rows bg*2, bg*2+1
    const int dir = blockIdx.y;
    const int tid = threadIdx.x;
    const unsigned* __restrict__ U16 = u16 + (size_t)dir * 131072;

    __shared__ unsigned hs16[2][128];
    __shared__ float    zs[2][1024];

    const int row0 = bg * 2;
    const int rr = tid >> 7;
    const int up = tid & 127;
    float c0r = 0.0f, c1r = 0.0f, h0r = 0.0f, h1r = 0.0f;
    if (tid < 256) {
        size_t base = ((size_t)dir * BATCH + row0 + rr) * HID + 2 * up;
        c0r = c_state[base];
        c1r = c_state[base + 1];
        float a = h_state[base];
        float b = h_state[base + 1];
        h0r = a; h1r = b;
        __half2 hh = __floats2half2_rn(a, b);
        hs16[rr][up] = *(unsigned*)&hh;
    }
    __syncthreads();

    for (int sl = 0; sl < chunk_len; ++sl) {
        const float* xwp = xw + (((size_t)dir * chunk_len + sl) * BATCH + row0) * G4;
        float acc0 = xwp[tid];
        float acc1 = xwp[G4 + tid];

        unsigned ub[16], un[16];
        #pragma unroll
        for (int j = 0; j < 16; ++j) ub[j] = U16[(size_t)j * G4 + tid];
        #pragma unroll
        for (int blk = 0; blk < 8; ++blk) {
            int nb = (blk + 1) & 7;
            #pragma unroll
            for (int j = 0; j < 16; ++j)
                un[j] = U16[(size_t)(nb * 16 + j) * G4 + tid];
            #pragma unroll
            for (int j = 0; j < 16; ++j) {
                int kp = blk * 16 + j;
                acc0 = fdot2_acc(hs16[0][kp], ub[j], acc0);
                acc1 = fdot2_acc(hs16[1][kp], ub[j], acc1);
            }
            #pragma unroll
            for (int j = 0; j < 16; ++j) ub[j] = un[j];
        }
        zs[0][tid] = acc0;
        zs[1][tid] = acc1;
        __syncthreads();

        if (tid < 256) {
            float zi0 = zs[rr][2 * up],       zi1 = zs[rr][2 * up + 1];
            float zf0 = zs[rr][256 + 2 * up], zf1 = zs[rr][256 + 2 * up + 1];
            float zg0 = zs[rr][512 + 2 * up], zg1 = zs[rr][512 + 2 * up + 1];
            float zo0 = zs[rr][768 + 2 * up], zo1 = zs[rr][768 + 2 * up + 1];
            float si0 = 1.0f / (1.0f + expf(-zi0)), si1 = 1.0f / (1.0f + expf(-zi1));
            float sf0 = 1.0f / (1.0f + expf(-zf0)), sf1 = 1.0f / (1.0f + expf(-zf1));
            float tg0 = tanhf(zg0),                 tg1 = tanhf(zg1);
            float so0 = 1.0f / (1.0f + expf(-zo0)), so1 = 1.0f / (1.0f + expf(-zo1));
            c0r = fmaf(sf0, c0r, si0 * tg0);
            c1r = fmaf(sf1, c1r, si1 * tg1);
            h0r = so0 * tanhf(c0r);
            h1r = so1 * tanhf(c1r);
            __half2 hh = __floats2half2_rn(h0r, h1r);
            hs16[rr][up] = *(unsigned*)&hh;
        }
        __syncthreads();
    }

    if (tid < 256) {
        size_t base = ((size_t)dir * BATCH + row0 + rr) * HID + 2 * up;
        h_state[base]     = h0r;
        h_state[base + 1] = h1r;
        c_state[base]     = c0r;
        c_state[base + 1] = c1r;
    }
}

// ---------------------------------------------------------------------------
// Fallback per-step kernel (v12 path) for tiny workspace.
// ---------------------------------------------------------------------------
__global__ __launch_bounds__(256) void lstm_step_fb(
    const int*   __restrict__ tokens,
    const float* __restrict__ emb_table,
    const float* __restrict__ W_f, const float* __restrict__ U_f, const float* __restrict__ b_f,
    const float* __restrict__ W_b, const float* __restrict__ U_b, const float* __restrict__ b_b,
    const float* __restrict__ h_in, float* __restrict__ h_out,
    float* __restrict__ c_state, int step)
{
    const int rt  = blockIdx.x;
    const int ut  = blockIdx.y;
    const int dir = blockIdx.z;
    const int tid = threadIdx.x;
    const float* __restrict__ W  = dir ? W_b : W_f;
    const float* __restrict__ U  = dir ? U_b : U_f;
    const float* __restrict__ bs = dir ? b_b : b_f;

    __shared__ int   tok[8];
    __shared__ float xs[8][260];
    __shared__ float hs[8][260];
    __shared__ float zsf[4][8][32];

    const int tt = dir ? (T_SEQ - 1 - step) : step;
    if (tid < 8) {
        int token = tokens[(rt * 8 + tid) * T_SEQ + tt];
        tok[tid] = (token < 0) ? 0 : (token > 49999 ? 49999 : token);
    }
    __syncthreads();
    for (int i = tid; i < 2048; i += 256) {
        int r = i >> 8, k = i & 255;
        xs[r][k] = emb_table[(size_t)tok[r] * 256 + k];
        hs[r][k] = h_in[((size_t)dir * BATCH + rt * 8 + r) * HID + k];
    }
    __syncthreads();

    const int g = tid >> 6, r = (tid >> 3) & 7, q = tid & 7;
    const int col = g * 256 + ut * 32 + q * 4;
    const float4* __restrict__ W4 = (const float4*)(W + col);
    const float4* __restrict__ U4 = (const float4*)(U + col);
    float4 acc = *(const float4*)(bs + col);
    #pragma unroll 4
    for (int k = 0; k < 256; ++k) {
        float xv = xs[r][k], hv = hs[r][k];
        float4 w = W4[(size_t)k * 256];
        float4 u = U4[(size_t)k * 256];
        acc.x = fmaf(xv, w.x, acc.x); acc.y = fmaf(xv, w.y, acc.y);
        acc.z = fmaf(xv, w.z, acc.z); acc.w = fmaf(xv, w.w, acc.w);
        acc.x = fmaf(hv, u.x, acc.x); acc.y = fmaf(hv, u.y, acc.y);
        acc.z = fmaf(hv, u.z, acc.z); acc.w = fmaf(hv, u.w, acc.w);
    }
    *(float4*)&zsf[g][r][q * 4] = acc;
    __syncthreads();
    {
        const int r2 = tid >> 5, j2 = tid & 31;
        float si = 1.0f / (1.0f + expf(-zsf[0][r2][j2]));
        float sf = 1.0f / (1.0f + expf(-zsf[1][r2][j2]));
        float tg = tanhf(zsf[2][r2][j2]);
        float so = 1.0f / (1.0f + expf(-zsf[3][r2][j2]));
        size_t idx = ((size_t)dir * BATCH + rt * 8 + r2) * HID + ut * 32 + j2;
        float cv = fmaf(sf, c_state[idx], si * tg);
        c_state[idx] = cv;
        h_out[idx] = so * tanhf(cv);
    }
}

// ---------------------------------------------------------------------------
// Dense + softmax (f32): one block per batch row.
// ---------------------------------------------------------------------------
__global__ __launch_bounds__(64) void dense_softmax_v18(
    const float* __restrict__ h_final,
    const float* __restrict__ W_d, const float* __restrict__ b_d,
    float* __restrict__ out)
{
    const int rrow = blockIdx.x;
    const int cth  = threadIdx.x;
    __shared__ float lg[NCLS];
    if (cth < NCLS) {
        const float* hf = h_final + (size_t)rrow * HID;
        const float* hb = h_final + ((size_t)BATCH + rrow) * HID;
        float s = b_d[cth];
        for (int k = 0; k < HID; ++k) s = fmaf(hf[k], W_d[k * NCLS + cth], s);
        for (int k = 0; k < HID; ++k) s = fmaf(hb[k], W_d[(HID + k) * NCLS + cth], s);
        lg[cth] = s;
    }
    __syncthreads();
    if (cth == 0) {
        float m = lg[0];
        for (int c = 1; c < NCLS; ++c) m = fmaxf(m, lg[c]);
        float e[NCLS]; float ssum = 0.0f;
        for (int c = 0; c < NCLS; ++c) { e[c] = expf(lg[c] - m); ssum += e[c]; }
        float inv = 1.0f / ssum;
        for (int c = 0; c < NCLS; ++c) out[rrow * NCLS + c] = e[c] * inv;
    }
}

extern "C" void kernel_launch(void* const* d_in, const int* in_sizes, int n_in,
                              void* d_out, int out_size, void* d_ws, size_t ws_size,
                              hipStream_t stream)
{
    const int*   tokens = (const int*)d_in[0];
    const float* emb    = (const float*)d_in[1];
    const float* W_f    = (const float*)d_in[2];
    const float* U_f    = (const float*)d_in[3];
    const float* b_f    = (const float*)d_in[4];
    const float* W_b    = (const float*)d_in[5];
    const float* U_b    = (const float*)d_in[6];
    const float* b_b    = (const float*)d_in[7];
    const float* W_d    = (const float*)d_in[8];
    const float* b_d    = (const float*)d_in[9];
    float* out = (float*)d_out;
    float* ws  = (float*)d_ws;

    const size_t HSLOT = (size_t)2 * BATCH * HID;        // 65536 floats
    const size_t U16SZ = (size_t)2 * 128 * G4;           // 262144 dwords
    int chunk = 0;
    const int cand[4] = {512, 128, 64, 16};
    for (int i = 0; i < 4; ++i) {
        size_t need = ((size_t)2 * cand[i] * BATCH * G4 + 2 * HSLOT + U16SZ) * sizeof(float);
        if (ws_size >= need) { chunk = cand[i]; break; }
    }

    if (chunk == 0) {
        float* hbuf0 = ws;
        float* cbuf  = hbuf0 + HSLOT;
        float* hbuf1 = cbuf + HSLOT;
        hipMemsetAsync(hbuf0, 0, 2 * HSLOT * sizeof(float), stream);
        float* hin = hbuf0; float* hout = hbuf1;
        for (int s = 0; s < T_SEQ; ++s) {
            lstm_step_fb<<<dim3(16, 8, 2), 256, 0, stream>>>(
                tokens, emb, W_f, U_f, b_f, W_b, U_b, b_b, hin, hout, cbuf, s);
            float* tmp = hin; hin = hout; hout = tmp;
        }
        dense_softmax_v18<<<dim3(BATCH), 64, 0, stream>>>(hin, W_d, b_d, out);
        return;
    }

    float*    xw     = ws;                                  // [2][chunk][128][1024]
    float*    hstate = xw + (size_t)2 * chunk * BATCH * G4; // [2][128][256]
    float*    cstate = hstate + HSLOT;                      // [2][128][256]
    unsigned* u16    = (unsigned*)(cstate + HSLOT);         // [2][128][1024]

    hipMemsetAsync(hstate, 0, 2 * HSLOT * sizeof(float), stream);  // h0 + c0

    pack_u16_v18<<<dim3(1024), 256, 0, stream>>>(U_f, U_b, u16);

    for (int c0 = 0; c0 < T_SEQ; c0 += chunk) {
        xw_gemm_mfma_v18<<<dim3(chunk * BATCH / 32, 4, 2), 256, 0, stream>>>(
            tokens, emb, W_f, b_f, W_b, b_b, xw, c0, chunk);
        lstm_scan_v18<<<dim3(64, 2), 1024, 0, stream>>>(
            xw, u16, hstate, cstate, chunk);
    }
    dense_softmax_v18<<<dim3(BATCH), 64, 0, stream>>>(hstate, W_d, b_d, out);
}

// Round 19
// 2266.543 us; speedup vs baseline: 3.9279x; 1.0136x over previous
//
#include <hip/hip_runtime.h>
#include <hip/hip_fp16.h>
#include <math.h>

#define T_SEQ  512
#define BATCH  128
#define HID    256
#define NCLS   20
#define G4     1024   // 4*HID

typedef _Float16 v2h   __attribute__((ext_vector_type(2)));
typedef _Float16 f16x8 __attribute__((ext_vector_type(8)));
typedef float    f32x4 __attribute__((ext_vector_type(4)));
typedef float    f32x2 __attribute__((ext_vector_type(2)));

__device__ __forceinline__ float fdot2_acc(unsigned a, unsigned b, float acc) {
#if __has_builtin(__builtin_amdgcn_fdot2)
    return __builtin_amdgcn_fdot2(__builtin_bit_cast(v2h, a),
                                  __builtin_bit_cast(v2h, b), acc, false);
#else
    __half2 a2 = __builtin_bit_cast(__half2, a);
    __half2 b2 = __builtin_bit_cast(__half2, b);
    acc = fmaf(__low2float(a2),  __low2float(b2),  acc);
    acc = fmaf(__high2float(a2), __high2float(b2), acc);
    return acc;
#endif
}

// unpack 4 e4m3fn bytes (dword) -> two f16x2 words (k,k+1), (k+2,k+3). Exact.
__device__ __forceinline__ void unpack_e4m3x4(unsigned q, unsigned &lo, unsigned &hi) {
#if __has_builtin(__builtin_amdgcn_cvt_pk_f32_fp8)
    f32x2 a = __builtin_amdgcn_cvt_pk_f32_fp8((int)q, false);
    f32x2 b = __builtin_amdgcn_cvt_pk_f32_fp8((int)q, true);
    v2h l; l[0] = (_Float16)a[0]; l[1] = (_Float16)a[1];   // exact: e4m3 ⊂ f16
    v2h h; h[0] = (_Float16)b[0]; h[1] = (_Float16)b[1];
    lo = __builtin_bit_cast(unsigned, l);
    hi = __builtin_bit_cast(unsigned, h);
#else
    // branchless integer unpack: place sign+7 bits, then *2^8 as f16 (exact,
    // handles subnormals): h16 = f16((b&0x80)<<8 | (b&0x7F)<<7) * 256
    unsigned w0 = ((q & 0x00000080u) << 8) | ((q & 0x0000007Fu) << 7)
                | ((q & 0x00008000u) << 16) | ((q & 0x00007F00u) << 15);
    unsigned w1 = (((q >> 16) & 0x00000080u) << 8) | (((q >> 16) & 0x0000007Fu) << 7)
                | (((q >> 16) & 0x00008000u) << 16) | (((q >> 16) & 0x00007F00u) << 15);
    v2h s = {(_Float16)256.0f, (_Float16)256.0f};
    v2h l = __builtin_bit_cast(v2h, w0) * s;
    v2h h = __builtin_bit_cast(v2h, w1) * s;
    lo = __builtin_bit_cast(unsigned, l);
    hi = __builtin_bit_cast(unsigned, h);
#endif
}

// manual RNE f32 -> e4m3fn (pack kernel only; speed irrelevant)
__device__ unsigned pack_e4m3(float v) {
    unsigned s = (__float_as_uint(v) >> 24) & 0x80u;
    float av = fabsf(v);
    if (!(av < 448.0f)) return s | 0x7Eu;         // clamp to max finite (448)
    if (av < 0.015625f) {                          // below 2^-6: subnormal
        int q = (int)rintf(av * 512.0f);           // RNE in units of 2^-9
        if (q <= 7) return s | (unsigned)q;
        return s | 0x08u;                          // rounds to min normal
    }
    int e; float man = frexpf(av, &e);             // av = man*2^e, man in [0.5,1)
    int q = (int)rintf(man * 16.0f);               // [8,16]
    int ebits = e - 1 + 7;
    if (q == 16) { q = 8; ebits += 1; }
    if (ebits > 15 || (ebits == 15 && q - 8 > 6)) return s | 0x7Eu;
    return s | ((unsigned)ebits << 3) | (unsigned)(q - 8);
}

// ---------------------------------------------------------------------------
// Pack U (f32 [256][1024]) -> e4m3 quads over k: u8[dir][kq][col] dwords,
// byte b of dword = e4m3(U[4*kq+b][col]).
// ---------------------------------------------------------------------------
__global__ __launch_bounds__(256) void pack_u8_v19(
    const float* __restrict__ U_f, const float* __restrict__ U_b,
    unsigned* __restrict__ u8out)
{
    int idx = blockIdx.x * 256 + threadIdx.x;    // 0 .. 2*64*1024-1
    if (idx >= 2 * 64 * 1024) return;
    int dir = idx >> 16;
    int rem = idx & 65535;
    int kq  = rem >> 10;
    int col = rem & 1023;
    const float* __restrict__ U = dir ? U_b : U_f;
    unsigned b0 = pack_e4m3(U[(size_t)(4 * kq + 0) * G4 + col]);
    unsigned b1 = pack_e4m3(U[(size_t)(4 * kq + 1) * G4 + col]);
    unsigned b2 = pack_e4m3(U[(size_t)(4 * kq + 2) * G4 + col]);
    unsigned b3 = pack_e4m3(U[(size_t)(4 * kq + 3) * G4 + col]);
    u8out[idx] = b0 | (b1 << 8) | (b2 << 16) | (b3 << 24);
}

// ---------------------------------------------------------------------------
// Kernel A: input projection via f16 MFMA 16x16x32 (v18, proven).
// ---------------------------------------------------------------------------
__global__ __launch_bounds__(256) void xw_gemm_mfma_v19(
    const int*   __restrict__ tokens,
    const float* __restrict__ emb_table,
    const float* __restrict__ W_f, const float* __restrict__ b_f,
    const float* __restrict__ W_b, const float* __restrict__ b_b,
    float* __restrict__ xw, int chunk0, int chunk_len)
{
    const int dir = blockIdx.z;
    const float* __restrict__ W    = dir ? W_b : W_f;
    const float* __restrict__ bias = dir ? b_b : b_f;
    const int mtile = blockIdx.x;
    const int ntile = blockIdx.y;          // 0..3
    const int tid = threadIdx.x;

    __shared__ _Float16 Ah[32][264];
    __shared__ _Float16 Wt[256][40];
    __shared__ int tok[32];

    if (tid < 32) {
        int m = mtile * 32 + tid;
        int s_local = m >> 7;
        int b = m & 127;
        int tt = chunk0 + s_local;
        if (dir) tt = T_SEQ - 1 - tt;
        int token = tokens[b * T_SEQ + tt];
        tok[tid] = token < 0 ? 0 : (token > 49999 ? 49999 : token);
    }
    __syncthreads();

    {
        int r = tid >> 3, c8 = tid & 7;
        const float4* src = (const float4*)(emb_table + (size_t)tok[r] * 256);
        #pragma unroll
        for (int i = 0; i < 8; ++i) {
            int c4 = c8 + i * 8;
            float4 v = src[c4];
            int k0 = c4 * 4;
            Ah[r][k0 + 0] = (_Float16)v.x;
            Ah[r][k0 + 1] = (_Float16)v.y;
            Ah[r][k0 + 2] = (_Float16)v.z;
            Ah[r][k0 + 3] = (_Float16)v.w;
        }
    }

    const int wv   = tid >> 6;
    const int lane = tid & 63;
    const int lr   = lane & 15;
    const int koff = (lane >> 4) * 8;
    const int n0   = wv * 64;

    f32x4 acc0[4], acc1[4];
    #pragma unroll
    for (int nf = 0; nf < 4; ++nf) {
        float bv = bias[ntile * 256 + n0 + nf * 16 + lr];
        acc0[nf] = (f32x4){bv, bv, bv, bv};
        acc1[nf] = (f32x4){bv, bv, bv, bv};
    }

    for (int kc = 0; kc < 8; ++kc) {
        __syncthreads();
        #pragma unroll
        for (int i = 0; i < 32; ++i) {
            int idx = tid + i * 256;
            int k = idx >> 8, n = idx & 255;
            Wt[n][k] = (_Float16)W[(size_t)(kc * 32 + k) * G4 + ntile * 256 + n];
        }
        __syncthreads();

        f16x8 a0 = *(const f16x8*)&Ah[lr][kc * 32 + koff];
        f16x8 a1 = *(const f16x8*)&Ah[16 + lr][kc * 32 + koff];
        #pragma unroll
        for (int nf = 0; nf < 4; ++nf) {
            f16x8 bf = *(const f16x8*)&Wt[n0 + nf * 16 + lr][koff];
            acc0[nf] = __builtin_amdgcn_mfma_f32_16x16x32_f16(a0, bf, acc0[nf], 0, 0, 0);
            acc1[nf] = __builtin_amdgcn_mfma_f32_16x16x32_f16(a1, bf, acc1[nf], 0, 0, 0);
        }
    }

    const int rbase = (lane >> 4) * 4;
    #pragma unroll
    for (int m = 0; m < 2; ++m) {
        #pragma unroll
        for (int nf = 0; nf < 4; ++nf) {
            f32x4 av = m ? acc1[nf] : acc0[nf];
            #pragma unroll
            for (int i = 0; i < 4; ++i) {
                int mrow = mtile * 32 + m * 16 + rbase + i;
                int s_local = mrow >> 7, b = mrow & 127;
                int col = ntile * 256 + n0 + nf * 16 + lr;
                xw[(((size_t)dir * chunk_len + s_local) * BATCH + b) * G4 + col] = av[i];
            }
        }
    }
}

// ---------------------------------------------------------------------------
// Kernel B: persistent scan with fp8 U (0.25 MB/block/step through L1).
// grid (bg=64, dir=2) x 1024 thr; block owns rows bg*2,+1; thread = 1 gate-col.
// ---------------------------------------------------------------------------
__global__ __launch_bounds__(1024) void lstm_scan_v19(
    const float* __restrict__ xw,          // [2][chunk][128][1024]
    const unsigned* __restrict__ u8,       // [2][64][1024]
    float* __restrict__ h_state,           // [2][128][256]
    float* __restrict__ c_state,           // [2][128][256]
    int chunk_len)
{
    const int bg  = blockIdx.x;
    const int dir = blockIdx.y;
    const int tid = threadIdx.x;
    const unsigned* __restrict__ U8 = u8 + (size_t)dir * 65536;

    __shared__ unsigned hs16[2][128];
    __shared__ float    zs[2][1024];

    const int row0 = bg * 2;
    const int rr = tid >> 7;
    const int up = tid & 127;
    float c0r = 0.0f, c1r = 0.0f, h0r = 0.0f, h1r = 0.0f;
    if (tid < 256) {
        size_t base = ((size_t)dir * BATCH + row0 + rr) * HID + 2 * up;
        c0r = c_state[base];
        c1r = c_state[base + 1];
        float a = h_state[base];
        float b = h_state[base + 1];
        h0r = a; h1r = b;
        __half2 hh = __floats2half2_rn(a, b);
        hs16[rr][up] = *(unsigned*)&hh;
    }
    __syncthreads();

    for (int sl = 0; sl < chunk_len; ++sl) {
        const float* xwp = xw + (((size_t)dir * chunk_len + sl) * BATCH + row0) * G4;
        float acc0 = xwp[tid];
        float acc1 = xwp[G4 + tid];

        unsigned ub[8], un[8];
        #pragma unroll
        for (int j = 0; j < 8; ++j) ub[j] = U8[(size_t)j * G4 + tid];
        #pragma unroll
        for (int blk = 0; blk < 8; ++blk) {
            int nb = (blk + 1) & 7;
            #pragma unroll
            for (int j = 0; j < 8; ++j)
                un[j] = U8[(size_t)(nb * 8 + j) * G4 + tid];
            #pragma unroll
            for (int j = 0; j < 8; ++j) {
                int kq = blk * 8 + j;
                unsigned ulo, uhi;
                unpack_e4m3x4(ub[j], ulo, uhi);
                acc0 = fdot2_acc(hs16[0][2 * kq],     ulo, acc0);
                acc0 = fdot2_acc(hs16[0][2 * kq + 1], uhi, acc0);
                acc1 = fdot2_acc(hs16[1][2 * kq],     ulo, acc1);
                acc1 = fdot2_acc(hs16[1][2 * kq + 1], uhi, acc1);
            }
            #pragma unroll
            for (int j = 0; j < 8; ++j) ub[j] = un[j];
        }
        zs[0][tid] = acc0;
        zs[1][tid] = acc1;
        __syncthreads();

        if (tid < 256) {
            float zi0 = zs[rr][2 * up],       zi1 = zs[rr][2 * up + 1];
            float zf0 = zs[rr][256 + 2 * up], zf1 = zs[rr][256 + 2 * up + 1];
            float zg0 = zs[rr][512 + 2 * up], zg1 = zs[rr][512 + 2 * up + 1];
            float zo0 = zs[rr][768 + 2 * up], zo1 = zs[rr][768 + 2 * up + 1];
            float si0 = 1.0f / (1.0f + expf(-zi0)), si1 = 1.0f / (1.0f + expf(-zi1));
            float sf0 = 1.0f / (1.0f + expf(-zf0)), sf1 = 1.0f / (1.0f + expf(-zf1));
            float tg0 = tanhf(zg0),                 tg1 = tanhf(zg1);
            float so0 = 1.0f / (1.0f + expf(-zo0)), so1 = 1.0f / (1.0f + expf(-zo1));
            c0r = fmaf(sf0, c0r, si0 * tg0);
            c1r = fmaf(sf1, c1r, si1 * tg1);
            h0r = so0 * tanhf(c0r);
            h1r = so1 * tanhf(c1r);
            __half2 hh = __floats2half2_rn(h0r, h1r);
            hs16[rr][up] = *(unsigned*)&hh;
        }
        __syncthreads();
    }

    if (tid < 256) {
        size_t base = ((size_t)dir * BATCH + row0 + rr) * HID + 2 * up;
        h_state[base]     = h0r;
        h_state[base + 1] = h1r;
        c_state[base]     = c0r;
        c_state[base + 1] = c1r;
    }
}

// ---------------------------------------------------------------------------
// Fallback per-step kernel (v12 path) for tiny workspace.
// ---------------------------------------------------------------------------
__global__ __launch_bounds__(256) void lstm_step_fb(
    const int*   __restrict__ tokens,
    const float* __restrict__ emb_table,
    const float* __restrict__ W_f, const float* __restrict__ U_f, const float* __restrict__ b_f,
    const float* __restrict__ W_b, const float* __restrict__ U_b, const float* __restrict__ b_b,
    const float* __restrict__ h_in, float* __restrict__ h_out,
    float* __restrict__ c_state, int step)
{
    const int rt  = blockIdx.x;
    const int ut  = blockIdx.y;
    const int dir = blockIdx.z;
    const int tid = threadIdx.x;
    const float* __restrict__ W  = dir ? W_b : W_f;
    const float* __restrict__ U  = dir ? U_b : U_f;
    const float* __restrict__ bs = dir ? b_b : b_f;

    __shared__ int   tok[8];
    __shared__ float xs[8][260];
    __shared__ float hs[8][260];
    __shared__ float zsf[4][8][32];

    const int tt = dir ? (T_SEQ - 1 - step) : step;
    if (tid < 8) {
        int token = tokens[(rt * 8 + tid) * T_SEQ + tt];
        tok[tid] = (token < 0) ? 0 : (token > 49999 ? 49999 : token);
    }
    __syncthreads();
    for (int i = tid; i < 2048; i += 256) {
        int r = i >> 8, k = i & 255;
        xs[r][k] = emb_table[(size_t)tok[r] * 256 + k];
        hs[r][k] = h_in[((size_t)dir * BATCH + rt * 8 + r) * HID + k];
    }
    __syncthreads();

    const int g = tid >> 6, r = (tid >> 3) & 7, q = tid & 7;
    const int col = g * 256 + ut * 32 + q * 4;
    const float4* __restrict__ W4 = (const float4*)(W + col);
    const float4* __restrict__ U4 = (const float4*)(U + col);
    float4 acc = *(const float4*)(bs + col);
    #pragma unroll 4
    for (int k = 0; k < 256; ++k) {
        float xv = xs[r][k], hv = hs[r][k];
        float4 w = W4[(size_t)k * 256];
        float4 u = U4[(size_t)k * 256];
        acc.x = fmaf(xv, w.x, acc.x); acc.y = fmaf(xv, w.y, acc.y);
        acc.z = fmaf(xv, w.z, acc.z); acc.w = fmaf(xv, w.w, acc.w);
        acc.x = fmaf(hv, u.x, acc.x); acc.y = fmaf(hv, u.y, acc.y);
        acc.z = fmaf(hv, u.z, acc.z); acc.w = fmaf(hv, u.w, acc.w);
    }
    *(float4*)&zsf[g][r][q * 4] = acc;
    __syncthreads();
    {
        const int r2 = tid >> 5, j2 = tid & 31;
        float si = 1.0f / (1.0f + expf(-zsf[0][r2][j2]));
        float sf = 1.0f / (1.0f + expf(-zsf[1][r2][j2]));
        float tg = tanhf(zsf[2][r2][j2]);
        float so = 1.0f / (1.0f + expf(-zsf[3][r2][j2]));
        size_t idx = ((size_t)dir * BATCH + rt * 8 + r2) * HID + ut * 32 + j2;
        float cv = fmaf(sf, c_state[idx], si * tg);
        c_state[idx] = cv;
        h_out[idx] = so * tanhf(cv);
    }
}

// ---------------------------------------------------------------------------
// Dense + softmax (f32): one block per batch row.
// ---------------------------------------------------------------------------
__global__ __launch_bounds__(64) void dense_softmax_v19(
    const float* __restrict__ h_final,
    const float* __restrict__ W_d, const float* __restrict__ b_d,
    float* __restrict__ out)
{
    const int rrow = blockIdx.x;
    const int cth  = threadIdx.x;
    __shared__ float lg[NCLS];
    if (cth < NCLS) {
        const float* hf = h_final + (size_t)rrow * HID;
        const float* hb = h_final + ((size_t)BATCH + rrow) * HID;
        float s = b_d[cth];
        for (int k = 0; k < HID; ++k) s = fmaf(hf[k], W_d[k * NCLS + cth], s);
        for (int k = 0; k < HID; ++k) s = fmaf(hb[k], W_d[(HID + k) * NCLS + cth], s);
        lg[cth] = s;
    }
    __syncthreads();
    if (cth == 0) {
        float m = lg[0];
        for (int c = 1; c < NCLS; ++c) m = fmaxf(m, lg[c]);
        float e[NCLS]; float ssum = 0.0f;
        for (int c = 0; c < NCLS; ++c) { e[c] = expf(lg[c] - m); ssum += e[c]; }
        float inv = 1.0f / ssum;
        for (int c = 0; c < NCLS; ++c) out[rrow * NCLS + c] = e[c] * inv;
    }
}

extern "C" void kernel_launch(void* const* d_in, const int* in_sizes, int n_in,
                              void* d_out, int out_size, void* d_ws, size_t ws_size,
                              hipStream_t stream)
{
    const int*   tokens = (const int*)d_in[0];
    const float* emb    = (const float*)d_in[1];
    const float* W_f    = (const float*)d_in[2];
    const float* U_f    = (const float*)d_in[3];
    const float* b_f    = (const float*)d_in[4];
    const float* W_b    = (const float*)d_in[5];
    const float* U_b    = (const float*)d_in[6];
    const float* b_b    = (const float*)d_in[7];
    const float* W_d    = (const float*)d_in[8];
    const float* b_d    = (const float*)d_in[9];
    float* out = (float*)d_out;
    float* ws  = (float*)d_ws;

    const size_t HSLOT = (size_t)2 * BATCH * HID;        // 65536 floats
    const size_t U8SZ  = (size_t)2 * 64 * G4;            // 131072 dwords
    int chunk = 0;
    const int cand[4] = {512, 128, 64, 16};
    for (int i = 0; i < 4; ++i) {
        size_t need = ((size_t)2 * cand[i] * BATCH * G4 + 2 * HSLOT + U8SZ) * sizeof(float);
        if (ws_size >= need) { chunk = cand[i]; break; }
    }

    if (chunk == 0) {
        float* hbuf0 = ws;
        float* cbuf  = hbuf0 + HSLOT;
        float* hbuf1 = cbuf + HSLOT;
        hipMemsetAsync(hbuf0, 0, 2 * HSLOT * sizeof(float), stream);
        float* hin = hbuf0; float* hout = hbuf1;
        for (int s = 0; s < T_SEQ; ++s) {
            lstm_step_fb<<<dim3(16, 8, 2), 256, 0, stream>>>(
                tokens, emb, W_f, U_f, b_f, W_b, U_b, b_b, hin, hout, cbuf, s);
            float* tmp = hin; hin = hout; hout = tmp;
        }
        dense_softmax_v19<<<dim3(BATCH), 64, 0, stream>>>(hin, W_d, b_d, out);
        return;
    }

    float*    xw     = ws;                                  // [2][chunk][128][1024]
    float*    hstate = xw + (size_t)2 * chunk * BATCH * G4; // [2][128][256]
    float*    cstate = hstate + HSLOT;                      // [2][128][256]
    unsigned* u8     = (unsigned*)(cstate + HSLOT);         // [2][64][1024]

    hipMemsetAsync(hstate, 0, 2 * HSLOT * sizeof(float), stream);  // h0 + c0

    pack_u8_v19<<<dim3(512), 256, 0, stream>>>(U_f, U_b, u8);

    for (int c0 = 0; c0 < T_SEQ; c0 += chunk) {
        xw_gemm_mfma_v19<<<dim3(chunk * BATCH / 32, 4, 2), 256, 0, stream>>>(
            tokens, emb, W_f, b_f, W_b, b_b, xw, c0, chunk);
        lstm_scan_v19<<<dim3(64, 2), 1024, 0, stream>>>(
            xw, u8, hstate, cstate, chunk);
    }
    dense_softmax_v19<<<dim3(BATCH), 64, 0, stream>>>(hstate, W_d, b_d, out);
}